// Round 1
// baseline (746.300 us; speedup 1.0000x reference)
//
#include <hip/hip_runtime.h>
#include <hip/hip_bf16.h>
#include <math.h>

// TwoAxisTransformerEncoderLayer — bs=8, R=128, C=64, E=256, H=8, hd=32, S=96, MLP=1024
// R6: gemm_mfma v3 — m97 structure: global_load_lds width=16 staging into linear
// [row][64] LDS tiles (2-barrier loop), XCD-aware bijective block swizzle
// (n-fastest so each XCD owns contiguous m-strips -> A L2 reuse).
// Epilogue (bias/gelu/res slab) and all other kernels unchanged from R5.

#define EDIM 256
#define HD   32
#define SCTX 96

typedef __bf16 bf16x8 __attribute__((ext_vector_type(8)));
typedef float  f32x4  __attribute__((ext_vector_type(4)));
union Frag { bf16x8 v; unsigned short u[8]; };

static __device__ __forceinline__ float b2f(unsigned short u) {
    return __uint_as_float(((unsigned int)u) << 16);
}
static __device__ __forceinline__ unsigned short f2b(float f) {
    unsigned int u = __float_as_uint(f);
    u += 0x7fffu + ((u >> 16) & 1u);           // RNE for finite values
    return (unsigned short)(u >> 16);
}

// async 16B global->LDS (DMA, no VGPR round-trip). dst must be wave-uniform;
// HW writes dst + lane*16.
static __device__ __forceinline__ void gload16(const unsigned short* g, unsigned short* l) {
    __builtin_amdgcn_global_load_lds(
        (const __attribute__((address_space(1))) unsigned int*)g,
        (__attribute__((address_space(3))) unsigned int*)l,
        16, 0, 0);
}

// ---------------------------------------------------------------- dtype detect
__global__ void detect_kernel(const unsigned int* __restrict__ n1g_raw,
                              int* __restrict__ flag) {
    *flag = (*n1g_raw == 0x3F800000u) ? 1 : 0;   // fp32 1.0f vs bf16 pair
}

// ---------------------------------------------------------------- weight pool convert
struct PtrTable { const void* p[18]; };

__global__ void cvt_kernel(PtrTable t, const int* __restrict__ flag,
                           unsigned short* __restrict__ wp) {
    const int seg_off[19] = {0, 196608, 197376, 262912, 263168, 459776, 460544,
                             526080, 526336, 788480, 789504, 1051648, 1051904,
                             1052160, 1052416, 1052672, 1052928, 1053184, 1053440};
    const int f = *flag;
    int idx = blockIdx.x * blockDim.x + threadIdx.x;
    int stride = gridDim.x * blockDim.x;
    for (int i = idx; i < 1053440; i += stride) {
        int s = 0;
        while (i >= seg_off[s + 1]) ++s;
        int j = i - seg_off[s];
        unsigned short o;
        if (f) o = f2b(((const float*)t.p[s])[j]);
        else   o = ((const unsigned short*)t.p[s])[j];
        wp[i] = o;
    }
}

// ---------------------------------------------------------------- nan_to_num + src convert
__global__ void prep_kernel(const void* __restrict__ src,
                            unsigned short* __restrict__ dst,
                            const int* __restrict__ flag, int n4) {
    const int f = *flag;
    int idx = blockIdx.x * blockDim.x + threadIdx.x;
    int stride = gridDim.x * blockDim.x;
    if (f) {
        const float4* s4 = (const float4*)src;
        for (int i = idx; i < n4; i += stride) {
            float4 v = s4[i];
            ushort4 o;
            o.x = ((__float_as_uint(v.x) & 0x7F800000u) == 0x7F800000u) ? 0 : f2b(v.x);
            o.y = ((__float_as_uint(v.y) & 0x7F800000u) == 0x7F800000u) ? 0 : f2b(v.y);
            o.z = ((__float_as_uint(v.z) & 0x7F800000u) == 0x7F800000u) ? 0 : f2b(v.z);
            o.w = ((__float_as_uint(v.w) & 0x7F800000u) == 0x7F800000u) ? 0 : f2b(v.w);
            ((ushort4*)dst)[i] = o;
        }
    } else {
        const ushort4* s4 = (const ushort4*)src;
        for (int i = idx; i < n4; i += stride) {
            ushort4 v = s4[i];
            if ((v.x & 0x7F80u) == 0x7F80u) v.x = 0;
            if ((v.y & 0x7F80u) == 0x7F80u) v.y = 0;
            if ((v.z & 0x7F80u) == 0x7F80u) v.z = 0;
            if ((v.w & 0x7F80u) == 0x7F80u) v.w = 0;
            ((ushort4*)dst)[i] = v;
        }
    }
}

// ---------------------------------------------------------------- MFMA GEMM v3 (m97 structure)
// out[m,n] = A[m,:K] . W[n,:K] (+bias) (gelu?) (+res[m,n]) -> bf16
// 128x128 tile / 256 threads (4 waves 2x2), BK=64, K % 64 == 0.
// LDS: linear As[128][64], Bs[128][64] bf16, staged by global_load_lds dwordx4
// (8 DMA issues/thread-step; lanes cover coalesced 128B row runs).
// 2-barrier loop (stage -> barrier(vmcnt drain) -> ds_read+MFMA -> barrier).
// Block swizzle: bijective chunked XCD map, n-tile fastest (A strip reuse in L2).
// Epilogue: bias/gelu in regs -> bf16 slab (32x136, aliases As) -> vectorized
// res-add + dwordx4 stores. pred: 0=all, 1=(m&127)<S, 2=(m&127)>=S.
__global__ __launch_bounds__(256) void gemm_mfma(
        const unsigned short* __restrict__ A, int lda,
        const unsigned short* __restrict__ W, int ldw,
        const unsigned short* __restrict__ bias,
        const unsigned short* __restrict__ res,
        unsigned short* __restrict__ out, int ldo,
        int K, int fuse, int pred, const int* __restrict__ splitp) {
    __shared__ __align__(16) unsigned short SH[16384];   // 32 KB
    unsigned short* Asb  = SH;            // [128][64] (16 KB)
    unsigned short* Bsb  = SH + 8192;     // [128][64]
    unsigned short* Slab = SH;            // 32x136 (aliases Asb, used post-mainloop)

    const int tid = threadIdx.x;

    // XCD-aware bijective chunked swizzle; all grids here are multiples of 8 blocks.
    // flat dispatch id round-robins XCDs -> (flat&7)*cpx + flat>>3 gives each XCD a
    // contiguous wgid chunk. Decompose n-fastest: the nT blocks sharing an A strip
    // are wgid-adjacent -> same XCD L2.
    const int nT   = gridDim.y;
    const int nwg  = gridDim.x * nT;
    const int flat = blockIdx.y * gridDim.x + blockIdx.x;
    const int cpx  = nwg >> 3;
    const int wgid = (flat & 7) * cpx + (flat >> 3);
    const int m0 = (wgid / nT) * 128;
    const int n0 = (wgid % nT) * 128;

    const int wave = tid >> 6;
    const int lane = tid & 63;
    const int wm = (wave >> 1) << 6;
    const int wn = (wave & 1) << 6;
    const int lm = lane & 15;
    const int lq = lane >> 4;

    // staging map: 16B slot s = j*256 + tid, row = s>>3, kcol = (s&7)*8
    const int rt = tid >> 3;              // row 0..31 (+32 per round j)
    const int ct = (tid & 7) * 8;         // k elem offset within 64-wide tile
    const unsigned short* Ag = A + (size_t)(m0 + rt) * lda + ct;
    const unsigned short* Wg = W + (size_t)(n0 + rt) * ldw + ct;
    const size_t a32 = (size_t)32 * lda, w32 = (size_t)32 * ldw;
    unsigned short* Adst = Asb + wave * 512;   // wave-uniform base, +2048 elems/round
    unsigned short* Bdst = Bsb + wave * 512;

    f32x4 acc[4][4] = {};
    for (int k0 = 0; k0 < K; k0 += 64) {
        __syncthreads();                       // prev iter frag reads complete
#pragma unroll
        for (int j = 0; j < 4; ++j) {
            gload16(Ag + j * a32 + k0, Adst + j * 2048);
            gload16(Wg + j * w32 + k0, Bdst + j * 2048);
        }
        __syncthreads();                       // DMA drained (vmcnt0 before s_barrier)
#pragma unroll
        for (int kk = 0; kk < 2; ++kk) {
            const int ko = kk * 32 + lq * 8;
            bf16x8 af[4], bq[4];
#pragma unroll
            for (int i = 0; i < 4; ++i)
                af[i] = *(const bf16x8*)&Asb[(wm + i * 16 + lm) * 64 + ko];
#pragma unroll
            for (int j = 0; j < 4; ++j)
                bq[j] = *(const bf16x8*)&Bsb[(wn + j * 16 + lm) * 64 + ko];
#pragma unroll
            for (int i = 0; i < 4; ++i)
#pragma unroll
                for (int j = 0; j < 4; ++j)
                    acc[i][j] = __builtin_amdgcn_mfma_f32_16x16x32_bf16(af[i], bq[j], acc[i][j], 0, 0, 0);
        }
    }
    __syncthreads();   // all frag reads done before Slab (aliases Asb) is written

    const int S = (pred != 0) ? *splitp : 0;
    float bv[4];
#pragma unroll
    for (int j = 0; j < 4; ++j)
        bv[j] = bias ? b2f(bias[n0 + wn + j * 16 + lm]) : 0.f;

    const int srow = (wave >> 1) * 16 + lq * 4;      // slab row base for this lane
    const int sr2 = tid >> 3;                        // readback slab row 0..31
    const int cc = (tid & 7) * 16;                   // readback col base
    const int mH = (sr2 >> 4) * 64 + (sr2 & 15);     // tile-row (minus i*16)

#pragma unroll
    for (int i = 0; i < 4; ++i) {
#pragma unroll
        for (int j = 0; j < 4; ++j)
#pragma unroll
            for (int r = 0; r < 4; ++r) {
                float x = acc[i][j][r] + bv[j];
                if (fuse == 1) x = 0.5f * x * (1.0f + erff(x * 0.70710678118654752f));
                Slab[(srow + r) * 136 + wn + j * 16 + lm] = f2b(x);
            }
        __syncthreads();
        {
            const int m = m0 + mH + i * 16;
            const int rr = m & 127;
            bool st = true;
            if (pred == 1 && rr >= S) st = false;
            if (pred == 2 && rr < S) st = false;
            if (st) {
#pragma unroll
                for (int h = 0; h < 2; ++h) {
                    uint4 v = *(const uint4*)&Slab[sr2 * 136 + cc + h * 8];
                    if (res) {
                        uint4 rv = *(const uint4*)(res + (size_t)m * 256 + n0 + cc + h * 8);
                        unsigned short* pv = (unsigned short*)&v;
                        const unsigned short* pr = (const unsigned short*)&rv;
#pragma unroll
                        for (int e = 0; e < 8; ++e)
                            pv[e] = f2b(b2f(pv[e]) + b2f(pr[e]));
                    }
                    *(uint4*)(out + (size_t)m * ldo + n0 + cc + h * 8) = v;
                }
            }
        }
        __syncthreads();
    }
}

// ---------------------------------------------------------------- RoPE on 8 consecutive dims
static __device__ __forceinline__ void rope8(float* t, int p0, float pos) {
#pragma unroll
    for (int p = 0; p < 4; ++p) {
        float invf = exp2f((float)(p0 + p) * -0.8304820237193385f);  // 10000^(-i/16)
        float ang = pos * invf;
        float c = __cosf(ang), s = __sinf(ang);
        float xe = t[2 * p], xo = t[2 * p + 1];
        t[2 * p]     = xe * c - xo * s;
        t[2 * p + 1] = xe * s + xo * c;
    }
}

// ---------------------------------------------------------------- MFMA attention (R4)
template<int NQT, int NKT, bool ROPE, bool BIAS>
__global__ __launch_bounds__(64) void attn_mfma(unsigned short* __restrict__ QKV,
                                                const int* __restrict__ mask,
                                                int seqlen, int qoff) {
    constexpr int NK = NKT * 16;
    constexpr int KS = NK / 32;
    const int s = blockIdx.x;
    const int h = blockIdx.y;
    const int lane = threadIdx.x;
    const int lm = lane & 15;
    const int lq = lane >> 4;
    const size_t rowbase = (size_t)s * seqlen;
    const float scale = 0.17677669529663689f;   // 1/sqrt(32)

    __shared__ __align__(16) unsigned short Vs[NK][40];
    __shared__ __align__(16) unsigned short Pt[16][104];
    __shared__ float bias_s[NK];

#pragma unroll
    for (int r0 = 0; r0 < NK; r0 += 16) {
        int r = r0 + (lane >> 2);
        int c = (lane & 3) * 8;
        uint4 v = *(const uint4*)(QKV + (rowbase + r) * 768 + 512 + h * 32 + c);
        *(uint4*)&Vs[r][c] = v;
    }
    if (BIAS) {
        const int b = s >> 6;
        for (int r = lane; r < NK; r += 64)
            bias_s[r] = (mask[b * 128 + r] > 0) ? 0.f : -1e9f;
    }
    Frag kf[NKT];
#pragma unroll
    for (int nt = 0; nt < NKT; ++nt) {
        const int krow = nt * 16 + lm;
        const unsigned short* kp = QKV + (rowbase + krow) * 768 + 256 + h * 32 + lq * 8;
        float t[8];
#pragma unroll
        for (int j = 0; j < 8; ++j) t[j] = b2f(kp[j]);
        if (ROPE) rope8(t, lq * 4, (float)krow);
#pragma unroll
        for (int j = 0; j < 8; ++j) kf[nt].u[j] = f2b(t[j]);
    }
    __syncthreads();
    Frag bvf[KS][2];
#pragma unroll
    for (int ks = 0; ks < KS; ++ks)
#pragma unroll
        for (int dt = 0; dt < 2; ++dt)
#pragma unroll
            for (int j = 0; j < 8; ++j)
                bvf[ks][dt].u[j] = Vs[ks * 32 + lq * 8 + j][dt * 16 + lm];

    for (int mt = 0; mt < NQT; ++mt) {
        Frag qf;
        const int qrow = qoff + mt * 16 + lm;
        {
            const unsigned short* qp = QKV + (rowbase + qrow) * 768 + h * 32 + lq * 8;
            float t[8];
#pragma unroll
            for (int j = 0; j < 8; ++j) t[j] = b2f(qp[j]);
            if (ROPE) rope8(t, lq * 4, (float)qrow);
#pragma unroll
            for (int j = 0; j < 8; ++j) qf.u[j] = f2b(t[j]);
        }
        f32x4 sacc[NKT] = {};
#pragma unroll
        for (int nt = 0; nt < NKT; ++nt)
            sacc[nt] = __builtin_amdgcn_mfma_f32_16x16x32_bf16(qf.v, kf[nt].v, sacc[nt], 0, 0, 0);
        float pv[NKT][4], mx[4], sm[4], inv[4];
#pragma unroll
        for (int r = 0; r < 4; ++r) mx[r] = -3.0e38f;
#pragma unroll
        for (int nt = 0; nt < NKT; ++nt)
#pragma unroll
            for (int r = 0; r < 4; ++r) {
                float x = sacc[nt][r] * scale;
                if (BIAS) x += bias_s[nt * 16 + lm];
                pv[nt][r] = x;
                mx[r] = fmaxf(mx[r], x);
            }
#pragma unroll
        for (int m = 1; m < 16; m <<= 1)
#pragma unroll
            for (int r = 0; r < 4; ++r) mx[r] = fmaxf(mx[r], __shfl_xor(mx[r], m, 64));
#pragma unroll
        for (int r = 0; r < 4; ++r) sm[r] = 0.f;
#pragma unroll
        for (int nt = 0; nt < NKT; ++nt)
#pragma unroll
            for (int r = 0; r < 4; ++r) {
                float p = __expf(pv[nt][r] - mx[r]);
                pv[nt][r] = p;
                sm[r] += p;
            }
#pragma unroll
        for (int m = 1; m < 16; m <<= 1)
#pragma unroll
            for (int r = 0; r < 4; ++r) sm[r] += __shfl_xor(sm[r], m, 64);
#pragma unroll
        for (int r = 0; r < 4; ++r) inv[r] = 1.f / sm[r];
#pragma unroll
        for (int nt = 0; nt < NKT; ++nt)
#pragma unroll
            for (int r = 0; r < 4; ++r)
                Pt[lq * 4 + r][nt * 16 + lm] = f2b(pv[nt][r] * inv[r]);
        __syncthreads();
        f32x4 oacc[2] = {};
#pragma unroll
        for (int ks = 0; ks < KS; ++ks) {
            Frag af;
            af.v = *(const bf16x8*)&Pt[lm][ks * 32 + lq * 8];
#pragma unroll
            for (int dt = 0; dt < 2; ++dt)
                oacc[dt] = __builtin_amdgcn_mfma_f32_16x16x32_bf16(af.v, bvf[ks][dt].v, oacc[dt], 0, 0, 0);
        }
#pragma unroll
        for (int dt = 0; dt < 2; ++dt)
#pragma unroll
            for (int r = 0; r < 4; ++r) {
                const int m = qoff + mt * 16 + lq * 4 + r;
                QKV[(rowbase + m) * 768 + h * 32 + dt * 16 + lm] = f2b(oacc[dt][r]);
            }
        __syncthreads();
    }
}

// ---------------------------------------------------------------- LayerNorm (+permute)
__global__ __launch_bounds__(64) void ln_permute_kernel(
        const unsigned short* __restrict__ X,
        const unsigned short* __restrict__ gam,
        const unsigned short* __restrict__ bet,
        void* __restrict__ Y, int mode, const int* __restrict__ flag) {
    const int t = blockIdx.x;
    const int tid = threadIdx.x;
    const int e = tid << 2;
    ushort4 xv = *(const ushort4*)(X + (size_t)t * EDIM + e);
    float v0 = b2f(xv.x), v1 = b2f(xv.y), v2 = b2f(xv.z), v3 = b2f(xv.w);
    float s = v0 + v1 + v2 + v3;
#pragma unroll
    for (int m = 32; m > 0; m >>= 1) s += __shfl_xor(s, m, 64);
    float mean = s * (1.f / EDIM);
    float d0 = v0 - mean, d1 = v1 - mean, d2 = v2 - mean, d3 = v3 - mean;
    float q = d0 * d0 + d1 * d1 + d2 * d2 + d3 * d3;
#pragma unroll
    for (int m = 32; m > 0; m >>= 1) q += __shfl_xor(q, m, 64);
    float rstd = rsqrtf(q * (1.f / EDIM) + 1e-5f);
    float g0 = b2f(gam[e]), g1 = b2f(gam[e + 1]), g2 = b2f(gam[e + 2]), g3 = b2f(gam[e + 3]);
    float b0 = b2f(bet[e]), b1 = b2f(bet[e + 1]), b2_ = b2f(bet[e + 2]), b3 = b2f(bet[e + 3]);
    float y0 = d0 * rstd * g0 + b0;
    float y1 = d1 * rstd * g1 + b1;
    float y2 = d2 * rstd * g2 + b2_;
    float y3 = d3 * rstd * g3 + b3;
    size_t drow;
    if (mode == 0) {
        int b = t >> 13, r = (t >> 6) & 127, c = t & 63;
        drow = ((size_t)b << 13) + ((size_t)c << 7) + (size_t)r;
    } else if (mode == 1) {
        int b = t >> 13, c = (t >> 7) & 63, r = t & 127;
        drow = ((size_t)b << 13) + ((size_t)r << 6) + (size_t)c;
    } else {
        drow = (size_t)t;
    }
    if (mode == 2 && *flag) {
        float4 o4 = make_float4(y0, y1, y2, y3);
        *(float4*)((float*)Y + drow * EDIM + e) = o4;
    } else {
        ushort4 o;
        o.x = f2b(y0); o.y = f2b(y1); o.z = f2b(y2); o.w = f2b(y3);
        *(ushort4*)((unsigned short*)Y + drow * EDIM + e) = o;
    }
}

// ---------------------------------------------------------------- launch
extern "C" void kernel_launch(void* const* d_in, const int* in_sizes, int n_in,
                              void* d_out, int out_size, void* d_ws, size_t ws_size,
                              hipStream_t stream) {
    (void)in_sizes; (void)n_in; (void)out_size; (void)ws_size;
    const void* src  = d_in[0];
    const int*  mask = (const int*)d_in[1];
    const int*  split= (const int*)d_in[2];

    int*            flag = (int*)d_ws;
    unsigned short* wp   = (unsigned short*)((char*)d_ws + 1024);
    unsigned short* Xa   = (unsigned short*)((char*)d_ws + (size_t)4 * 1024 * 1024);
    unsigned short* Xb   = Xa + (size_t)16777216;
    unsigned short* QKV  = Xb + (size_t)16777216;
    unsigned short* HID  = QKV;

    const unsigned short* y_in_w  = wp + 0;
    const unsigned short* y_in_b  = wp + 196608;
    const unsigned short* y_out_w = wp + 197376;
    const unsigned short* y_out_b = wp + 262912;
    const unsigned short* x_in_w  = wp + 263168;
    const unsigned short* x_in_b  = wp + 459776;
    const unsigned short* x_out_w = wp + 460544;
    const unsigned short* x_out_b = wp + 526080;
    const unsigned short* w1      = wp + 526336;
    const unsigned short* b1      = wp + 788480;
    const unsigned short* w2      = wp + 789504;
    const unsigned short* b2      = wp + 1051648;
    const unsigned short* n1_g    = wp + 1051904;
    const unsigned short* n1_b    = wp + 1052160;
    const unsigned short* n2_g    = wp + 1052416;
    const unsigned short* n2_b    = wp + 1052672;
    const unsigned short* n3_g    = wp + 1052928;
    const unsigned short* n3_b    = wp + 1053184;

    detect_kernel<<<1, 1, 0, stream>>>((const unsigned int*)d_in[15], flag);

    PtrTable pt;
    for (int i = 0; i < 18; ++i) pt.p[i] = d_in[3 + i];
    cvt_kernel<<<512, 256, 0, stream>>>(pt, flag, wp);

    // phase 0: nan_to_num + convert
    prep_kernel<<<4096, 256, 0, stream>>>(src, Xa, flag, 4194304);
    // phase 1: Y-axis self-attention (seq = C = 64)
    gemm_mfma<<<dim3(512, 6), 256, 0, stream>>>(Xa, 256, y_in_w, 256, y_in_b, nullptr, QKV, 768, 256, 0, 0, nullptr);
    attn_mfma<4, 4, false, false><<<dim3(1024, 8), 64, 0, stream>>>(QKV, mask, 64, 0);
    gemm_mfma<<<dim3(512, 2), 256, 0, stream>>>(QKV, 768, y_out_w, 256, y_out_b, Xa, Xa, 256, 256, 0, 0, nullptr);
    ln_permute_kernel<<<65536, 64, 0, stream>>>(Xa, n1_g, n1_b, Xb, 0, flag);
    // phase 2: X-axis attention (seq = R = 128, split S = 96)
    gemm_mfma<<<dim3(512, 6), 256, 0, stream>>>(Xb, 256, x_in_w, 256, x_in_b, nullptr, QKV, 768, 256, 0, 0, nullptr);
    attn_mfma<6, 6, true, true><<<dim3(512, 8), 64, 0, stream>>>(QKV, mask, 128, 0);
    gemm_mfma<<<dim3(512, 2), 256, 0, stream>>>(QKV, 768, x_out_w, 256, x_out_b, Xb, Xb, 256, 256, 0, 1, split);
    // second X QKV: only k,v (cols 256..768) need recompute — q of qry rows is intact
    gemm_mfma<<<dim3(512, 4), 256, 0, stream>>>(Xb, 256, x_in_w + 65536, 256, x_in_b + 256, nullptr, QKV + 256, 768, 256, 0, 0, nullptr);
    attn_mfma<2, 6, true, true><<<dim3(512, 8), 64, 0, stream>>>(QKV, mask, 128, 96);
    gemm_mfma<<<dim3(512, 2), 256, 0, stream>>>(QKV, 768, x_out_w, 256, x_out_b, Xb, Xb, 256, 256, 0, 2, split);
    ln_permute_kernel<<<65536, 64, 0, stream>>>(Xb, n2_g, n2_b, Xa, 1, flag);
    // phase 3: MLP (hidden split in two 512-halves, HID reuses QKV region)
    gemm_mfma<<<dim3(512, 4), 256, 0, stream>>>(Xa, 256, w1, 256, b1, nullptr, HID, 512, 256, 1, 0, nullptr);
    gemm_mfma<<<dim3(512, 2), 256, 0, stream>>>(HID, 512, w2, 1024, b2, Xa, Xb, 256, 512, 0, 0, nullptr);
    gemm_mfma<<<dim3(512, 4), 256, 0, stream>>>(Xa, 256, w1 + 512 * 256, 256, b1 + 512, nullptr, HID, 512, 256, 1, 0, nullptr);
    gemm_mfma<<<dim3(512, 2), 256, 0, stream>>>(HID, 512, w2 + 512, 1024, nullptr, Xb, Xb, 256, 512, 0, 0, nullptr);
    // phase 4: LN3 -> output (dtype per flag)
    ln_permute_kernel<<<65536, 64, 0, stream>>>(Xb, n3_g, n3_b, d_out, 2, flag);
}

// Round 2
// 725.179 us; speedup vs baseline: 1.0291x; 1.0291x over previous
//
#include <hip/hip_runtime.h>
#include <hip/hip_bf16.h>
#include <math.h>

// TwoAxisTransformerEncoderLayer — bs=8, R=128, C=64, E=256, H=8, hd=32, S=96, MLP=1024
// R7: gemm_mfma v4 — double-buffered global_load_lds pipeline ("minimum 2-phase"
// T3): stage tile t+1 BEFORE computing tile t, single barrier per K-step (its
// implicit vmcnt(0) drain IS the pipeline sync). LDS 64 KB (A0|B0|A1|B1).
// Keeps R6's XCD-aware bijective swizzle (FETCH 77.7->18.2 MB verified).
// Epilogue (bias/gelu/res slab) and all other kernels unchanged.

#define EDIM 256
#define HD   32
#define SCTX 96

typedef __bf16 bf16x8 __attribute__((ext_vector_type(8)));
typedef float  f32x4  __attribute__((ext_vector_type(4)));
union Frag { bf16x8 v; unsigned short u[8]; };

static __device__ __forceinline__ float b2f(unsigned short u) {
    return __uint_as_float(((unsigned int)u) << 16);
}
static __device__ __forceinline__ unsigned short f2b(float f) {
    unsigned int u = __float_as_uint(f);
    u += 0x7fffu + ((u >> 16) & 1u);           // RNE for finite values
    return (unsigned short)(u >> 16);
}

// async 16B global->LDS (DMA, no VGPR round-trip). dst must be wave-uniform;
// HW writes dst + lane*16.
static __device__ __forceinline__ void gload16(const unsigned short* g, unsigned short* l) {
    __builtin_amdgcn_global_load_lds(
        (const __attribute__((address_space(1))) unsigned int*)g,
        (__attribute__((address_space(3))) unsigned int*)l,
        16, 0, 0);
}

// ---------------------------------------------------------------- dtype detect
__global__ void detect_kernel(const unsigned int* __restrict__ n1g_raw,
                              int* __restrict__ flag) {
    *flag = (*n1g_raw == 0x3F800000u) ? 1 : 0;   // fp32 1.0f vs bf16 pair
}

// ---------------------------------------------------------------- weight pool convert
struct PtrTable { const void* p[18]; };

__global__ void cvt_kernel(PtrTable t, const int* __restrict__ flag,
                           unsigned short* __restrict__ wp) {
    const int seg_off[19] = {0, 196608, 197376, 262912, 263168, 459776, 460544,
                             526080, 526336, 788480, 789504, 1051648, 1051904,
                             1052160, 1052416, 1052672, 1052928, 1053184, 1053440};
    const int f = *flag;
    int idx = blockIdx.x * blockDim.x + threadIdx.x;
    int stride = gridDim.x * blockDim.x;
    for (int i = idx; i < 1053440; i += stride) {
        int s = 0;
        while (i >= seg_off[s + 1]) ++s;
        int j = i - seg_off[s];
        unsigned short o;
        if (f) o = f2b(((const float*)t.p[s])[j]);
        else   o = ((const unsigned short*)t.p[s])[j];
        wp[i] = o;
    }
}

// ---------------------------------------------------------------- nan_to_num + src convert
__global__ void prep_kernel(const void* __restrict__ src,
                            unsigned short* __restrict__ dst,
                            const int* __restrict__ flag, int n4) {
    const int f = *flag;
    int idx = blockIdx.x * blockDim.x + threadIdx.x;
    int stride = gridDim.x * blockDim.x;
    if (f) {
        const float4* s4 = (const float4*)src;
        for (int i = idx; i < n4; i += stride) {
            float4 v = s4[i];
            ushort4 o;
            o.x = ((__float_as_uint(v.x) & 0x7F800000u) == 0x7F800000u) ? 0 : f2b(v.x);
            o.y = ((__float_as_uint(v.y) & 0x7F800000u) == 0x7F800000u) ? 0 : f2b(v.y);
            o.z = ((__float_as_uint(v.z) & 0x7F800000u) == 0x7F800000u) ? 0 : f2b(v.z);
            o.w = ((__float_as_uint(v.w) & 0x7F800000u) == 0x7F800000u) ? 0 : f2b(v.w);
            ((ushort4*)dst)[i] = o;
        }
    } else {
        const ushort4* s4 = (const ushort4*)src;
        for (int i = idx; i < n4; i += stride) {
            ushort4 v = s4[i];
            if ((v.x & 0x7F80u) == 0x7F80u) v.x = 0;
            if ((v.y & 0x7F80u) == 0x7F80u) v.y = 0;
            if ((v.z & 0x7F80u) == 0x7F80u) v.z = 0;
            if ((v.w & 0x7F80u) == 0x7F80u) v.w = 0;
            ((ushort4*)dst)[i] = v;
        }
    }
}

// ---------------------------------------------------------------- MFMA GEMM v4
// out[m,n] = A[m,:K] . W[n,:K] (+bias) (gelu?) (+res[m,n]) -> bf16
// 128x128 tile / 256 threads (4 waves 2x2), BK=64, K % 64 == 0.
// LDS: 64 KB = double-buffered linear [row][64] A,B tiles, staged by
// global_load_lds dwordx4. Pipeline: STAGE(t+1) -> compute(t) -> barrier
// (implicit vmcnt(0) drain = tile t+1 ready + buffer-reuse guard).
// Block swizzle: bijective chunked XCD map, n-tile fastest (A strip L2 reuse).
// Epilogue: bias/gelu in regs -> bf16 slab (32x136, aliases LDS) -> vectorized
// res-add + dwordx4 stores. pred: 0=all, 1=(m&127)<S, 2=(m&127)>=S.
__global__ __launch_bounds__(256) void gemm_mfma(
        const unsigned short* __restrict__ A, int lda,
        const unsigned short* __restrict__ W, int ldw,
        const unsigned short* __restrict__ bias,
        const unsigned short* __restrict__ res,
        unsigned short* __restrict__ out, int ldo,
        int K, int fuse, int pred, const int* __restrict__ splitp) {
    __shared__ __align__(16) unsigned short SH[32768];   // 64 KB: A0|B0|A1|B1
    unsigned short* Slab = SH;            // 32x136 (aliases buf0, used post-mainloop)

    const int tid = threadIdx.x;

    // XCD-aware bijective chunked swizzle; all grids here are multiples of 8 blocks.
    const int nT   = gridDim.y;
    const int nwg  = gridDim.x * nT;
    const int flat = blockIdx.y * gridDim.x + blockIdx.x;
    const int cpx  = nwg >> 3;
    const int wgid = (flat & 7) * cpx + (flat >> 3);
    const int m0 = (wgid / nT) * 128;
    const int n0 = (wgid % nT) * 128;

    const int wave = tid >> 6;
    const int lane = tid & 63;
    const int wm = (wave >> 1) << 6;
    const int wn = (wave & 1) << 6;
    const int lm = lane & 15;
    const int lq = lane >> 4;

    // staging map: 16B slot = tid (8 elems), row = tid>>3, kcol = (tid&7)*8
    const int rt = tid >> 3;              // row 0..31 (+32 per round j)
    const int ct = (tid & 7) * 8;         // k elem offset within 64-wide tile
    const unsigned short* Ag = A + (size_t)(m0 + rt) * lda + ct;
    const unsigned short* Wg = W + (size_t)(n0 + rt) * ldw + ct;
    const size_t a32 = (size_t)32 * lda, w32 = (size_t)32 * ldw;
    const int wofs = wave * 512;          // wave-uniform LDS base (+2048/round)

    f32x4 acc[4][4] = {};
    const int nk = K >> 6;

    // prologue: stage tile 0 into buf 0
#pragma unroll
    for (int j = 0; j < 4; ++j) {
        gload16(Ag + j * a32, SH + wofs + j * 2048);
        gload16(Wg + j * w32, SH + 8192 + wofs + j * 2048);
    }
    __syncthreads();

    int cur = 0;
    for (int t = 0; t < nk; ++t) {
        if (t + 1 < nk) {                  // issue next tile's DMA (in flight under MFMA)
            const int kn = (t + 1) << 6;
            unsigned short* Ad = SH + ((cur ^ 1) << 14) + wofs;
#pragma unroll
            for (int j = 0; j < 4; ++j) {
                gload16(Ag + j * a32 + kn, Ad + j * 2048);
                gload16(Wg + j * w32 + kn, Ad + 8192 + j * 2048);
            }
        }
        const unsigned short* As = SH + (cur << 14);
        const unsigned short* Bs = As + 8192;
#pragma unroll
        for (int kk = 0; kk < 2; ++kk) {
            const int ko = kk * 32 + lq * 8;
            bf16x8 af[4], bq[4];
#pragma unroll
            for (int i = 0; i < 4; ++i)
                af[i] = *(const bf16x8*)&As[(wm + i * 16 + lm) * 64 + ko];
#pragma unroll
            for (int j = 0; j < 4; ++j)
                bq[j] = *(const bf16x8*)&Bs[(wn + j * 16 + lm) * 64 + ko];
#pragma unroll
            for (int i = 0; i < 4; ++i)
#pragma unroll
                for (int j = 0; j < 4; ++j)
                    acc[i][j] = __builtin_amdgcn_mfma_f32_16x16x32_bf16(af[i], bq[j], acc[i][j], 0, 0, 0);
        }
        __syncthreads();                   // drains vmcnt: tile t+1 ready; reads done
        cur ^= 1;
    }

    const int S = (pred != 0) ? *splitp : 0;
    float bv[4];
#pragma unroll
    for (int j = 0; j < 4; ++j)
        bv[j] = bias ? b2f(bias[n0 + wn + j * 16 + lm]) : 0.f;

    const int srow = (wave >> 1) * 16 + lq * 4;      // slab row base for this lane
    const int sr2 = tid >> 3;                        // readback slab row 0..31
    const int cc = (tid & 7) * 16;                   // readback col base
    const int mH = (sr2 >> 4) * 64 + (sr2 & 15);     // tile-row (minus i*16)

#pragma unroll
    for (int i = 0; i < 4; ++i) {
#pragma unroll
        for (int j = 0; j < 4; ++j)
#pragma unroll
            for (int r = 0; r < 4; ++r) {
                float x = acc[i][j][r] + bv[j];
                if (fuse == 1) x = 0.5f * x * (1.0f + erff(x * 0.70710678118654752f));
                Slab[(srow + r) * 136 + wn + j * 16 + lm] = f2b(x);
            }
        __syncthreads();
        {
            const int m = m0 + mH + i * 16;
            const int rr = m & 127;
            bool st = true;
            if (pred == 1 && rr >= S) st = false;
            if (pred == 2 && rr < S) st = false;
            if (st) {
#pragma unroll
                for (int h = 0; h < 2; ++h) {
                    uint4 v = *(const uint4*)&Slab[sr2 * 136 + cc + h * 8];
                    if (res) {
                        uint4 rv = *(const uint4*)(res + (size_t)m * 256 + n0 + cc + h * 8);
                        unsigned short* pv = (unsigned short*)&v;
                        const unsigned short* pr = (const unsigned short*)&rv;
#pragma unroll
                        for (int e = 0; e < 8; ++e)
                            pv[e] = f2b(b2f(pv[e]) + b2f(pr[e]));
                    }
                    *(uint4*)(out + (size_t)m * ldo + n0 + cc + h * 8) = v;
                }
            }
        }
        __syncthreads();
    }
}

// ---------------------------------------------------------------- RoPE on 8 consecutive dims
static __device__ __forceinline__ void rope8(float* t, int p0, float pos) {
#pragma unroll
    for (int p = 0; p < 4; ++p) {
        float invf = exp2f((float)(p0 + p) * -0.8304820237193385f);  // 10000^(-i/16)
        float ang = pos * invf;
        float c = __cosf(ang), s = __sinf(ang);
        float xe = t[2 * p], xo = t[2 * p + 1];
        t[2 * p]     = xe * c - xo * s;
        t[2 * p + 1] = xe * s + xo * c;
    }
}

// ---------------------------------------------------------------- MFMA attention (R4)
template<int NQT, int NKT, bool ROPE, bool BIAS>
__global__ __launch_bounds__(64) void attn_mfma(unsigned short* __restrict__ QKV,
                                                const int* __restrict__ mask,
                                                int seqlen, int qoff) {
    constexpr int NK = NKT * 16;
    constexpr int KS = NK / 32;
    const int s = blockIdx.x;
    const int h = blockIdx.y;
    const int lane = threadIdx.x;
    const int lm = lane & 15;
    const int lq = lane >> 4;
    const size_t rowbase = (size_t)s * seqlen;
    const float scale = 0.17677669529663689f;   // 1/sqrt(32)

    __shared__ __align__(16) unsigned short Vs[NK][40];
    __shared__ __align__(16) unsigned short Pt[16][104];
    __shared__ float bias_s[NK];

#pragma unroll
    for (int r0 = 0; r0 < NK; r0 += 16) {
        int r = r0 + (lane >> 2);
        int c = (lane & 3) * 8;
        uint4 v = *(const uint4*)(QKV + (rowbase + r) * 768 + 512 + h * 32 + c);
        *(uint4*)&Vs[r][c] = v;
    }
    if (BIAS) {
        const int b = s >> 6;
        for (int r = lane; r < NK; r += 64)
            bias_s[r] = (mask[b * 128 + r] > 0) ? 0.f : -1e9f;
    }
    Frag kf[NKT];
#pragma unroll
    for (int nt = 0; nt < NKT; ++nt) {
        const int krow = nt * 16 + lm;
        const unsigned short* kp = QKV + (rowbase + krow) * 768 + 256 + h * 32 + lq * 8;
        float t[8];
#pragma unroll
        for (int j = 0; j < 8; ++j) t[j] = b2f(kp[j]);
        if (ROPE) rope8(t, lq * 4, (float)krow);
#pragma unroll
        for (int j = 0; j < 8; ++j) kf[nt].u[j] = f2b(t[j]);
    }
    __syncthreads();
    Frag bvf[KS][2];
#pragma unroll
    for (int ks = 0; ks < KS; ++ks)
#pragma unroll
        for (int dt = 0; dt < 2; ++dt)
#pragma unroll
            for (int j = 0; j < 8; ++j)
                bvf[ks][dt].u[j] = Vs[ks * 32 + lq * 8 + j][dt * 16 + lm];

    for (int mt = 0; mt < NQT; ++mt) {
        Frag qf;
        const int qrow = qoff + mt * 16 + lm;
        {
            const unsigned short* qp = QKV + (rowbase + qrow) * 768 + h * 32 + lq * 8;
            float t[8];
#pragma unroll
            for (int j = 0; j < 8; ++j) t[j] = b2f(qp[j]);
            if (ROPE) rope8(t, lq * 4, (float)qrow);
#pragma unroll
            for (int j = 0; j < 8; ++j) qf.u[j] = f2b(t[j]);
        }
        f32x4 sacc[NKT] = {};
#pragma unroll
        for (int nt = 0; nt < NKT; ++nt)
            sacc[nt] = __builtin_amdgcn_mfma_f32_16x16x32_bf16(qf.v, kf[nt].v, sacc[nt], 0, 0, 0);
        float pv[NKT][4], mx[4], sm[4], inv[4];
#pragma unroll
        for (int r = 0; r < 4; ++r) mx[r] = -3.0e38f;
#pragma unroll
        for (int nt = 0; nt < NKT; ++nt)
#pragma unroll
            for (int r = 0; r < 4; ++r) {
                float x = sacc[nt][r] * scale;
                if (BIAS) x += bias_s[nt * 16 + lm];
                pv[nt][r] = x;
                mx[r] = fmaxf(mx[r], x);
            }
#pragma unroll
        for (int m = 1; m < 16; m <<= 1)
#pragma unroll
            for (int r = 0; r < 4; ++r) mx[r] = fmaxf(mx[r], __shfl_xor(mx[r], m, 64));
#pragma unroll
        for (int r = 0; r < 4; ++r) sm[r] = 0.f;
#pragma unroll
        for (int nt = 0; nt < NKT; ++nt)
#pragma unroll
            for (int r = 0; r < 4; ++r) {
                float p = __expf(pv[nt][r] - mx[r]);
                pv[nt][r] = p;
                sm[r] += p;
            }
#pragma unroll
        for (int m = 1; m < 16; m <<= 1)
#pragma unroll
            for (int r = 0; r < 4; ++r) sm[r] += __shfl_xor(sm[r], m, 64);
#pragma unroll
        for (int r = 0; r < 4; ++r) inv[r] = 1.f / sm[r];
#pragma unroll
        for (int nt = 0; nt < NKT; ++nt)
#pragma unroll
            for (int r = 0; r < 4; ++r)
                Pt[lq * 4 + r][nt * 16 + lm] = f2b(pv[nt][r] * inv[r]);
        __syncthreads();
        f32x4 oacc[2] = {};
#pragma unroll
        for (int ks = 0; ks < KS; ++ks) {
            Frag af;
            af.v = *(const bf16x8*)&Pt[lm][ks * 32 + lq * 8];
#pragma unroll
            for (int dt = 0; dt < 2; ++dt)
                oacc[dt] = __builtin_amdgcn_mfma_f32_16x16x32_bf16(af.v, bvf[ks][dt].v, oacc[dt], 0, 0, 0);
        }
#pragma unroll
        for (int dt = 0; dt < 2; ++dt)
#pragma unroll
            for (int r = 0; r < 4; ++r) {
                const int m = qoff + mt * 16 + lq * 4 + r;
                QKV[(rowbase + m) * 768 + h * 32 + dt * 16 + lm] = f2b(oacc[dt][r]);
            }
        __syncthreads();
    }
}

// ---------------------------------------------------------------- LayerNorm (+permute)
__global__ __launch_bounds__(64) void ln_permute_kernel(
        const unsigned short* __restrict__ X,
        const unsigned short* __restrict__ gam,
        const unsigned short* __restrict__ bet,
        void* __restrict__ Y, int mode, const int* __restrict__ flag) {
    const int t = blockIdx.x;
    const int tid = threadIdx.x;
    const int e = tid << 2;
    ushort4 xv = *(const ushort4*)(X + (size_t)t * EDIM + e);
    float v0 = b2f(xv.x), v1 = b2f(xv.y), v2 = b2f(xv.z), v3 = b2f(xv.w);
    float s = v0 + v1 + v2 + v3;
#pragma unroll
    for (int m = 32; m > 0; m >>= 1) s += __shfl_xor(s, m, 64);
    float mean = s * (1.f / EDIM);
    float d0 = v0 - mean, d1 = v1 - mean, d2 = v2 - mean, d3 = v3 - mean;
    float q = d0 * d0 + d1 * d1 + d2 * d2 + d3 * d3;
#pragma unroll
    for (int m = 32; m > 0; m >>= 1) q += __shfl_xor(q, m, 64);
    float rstd = rsqrtf(q * (1.f / EDIM) + 1e-5f);
    float g0 = b2f(gam[e]), g1 = b2f(gam[e + 1]), g2 = b2f(gam[e + 2]), g3 = b2f(gam[e + 3]);
    float b0 = b2f(bet[e]), b1 = b2f(bet[e + 1]), b2_ = b2f(bet[e + 2]), b3 = b2f(bet[e + 3]);
    float y0 = d0 * rstd * g0 + b0;
    float y1 = d1 * rstd * g1 + b1;
    float y2 = d2 * rstd * g2 + b2_;
    float y3 = d3 * rstd * g3 + b3;
    size_t drow;
    if (mode == 0) {
        int b = t >> 13, r = (t >> 6) & 127, c = t & 63;
        drow = ((size_t)b << 13) + ((size_t)c << 7) + (size_t)r;
    } else if (mode == 1) {
        int b = t >> 13, c = (t >> 7) & 63, r = t & 127;
        drow = ((size_t)b << 13) + ((size_t)r << 6) + (size_t)c;
    } else {
        drow = (size_t)t;
    }
    if (mode == 2 && *flag) {
        float4 o4 = make_float4(y0, y1, y2, y3);
        *(float4*)((float*)Y + drow * EDIM + e) = o4;
    } else {
        ushort4 o;
        o.x = f2b(y0); o.y = f2b(y1); o.z = f2b(y2); o.w = f2b(y3);
        *(ushort4*)((unsigned short*)Y + drow * EDIM + e) = o;
    }
}

// ---------------------------------------------------------------- launch
extern "C" void kernel_launch(void* const* d_in, const int* in_sizes, int n_in,
                              void* d_out, int out_size, void* d_ws, size_t ws_size,
                              hipStream_t stream) {
    (void)in_sizes; (void)n_in; (void)out_size; (void)ws_size;
    const void* src  = d_in[0];
    const int*  mask = (const int*)d_in[1];
    const int*  split= (const int*)d_in[2];

    int*            flag = (int*)d_ws;
    unsigned short* wp   = (unsigned short*)((char*)d_ws + 1024);
    unsigned short* Xa   = (unsigned short*)((char*)d_ws + (size_t)4 * 1024 * 1024);
    unsigned short* Xb   = Xa + (size_t)16777216;
    unsigned short* QKV  = Xb + (size_t)16777216;
    unsigned short* HID  = QKV;

    const unsigned short* y_in_w  = wp + 0;
    const unsigned short* y_in_b  = wp + 196608;
    const unsigned short* y_out_w = wp + 197376;
    const unsigned short* y_out_b = wp + 262912;
    const unsigned short* x_in_w  = wp + 263168;
    const unsigned short* x_in_b  = wp + 459776;
    const unsigned short* x_out_w = wp + 460544;
    const unsigned short* x_out_b = wp + 526080;
    const unsigned short* w1      = wp + 526336;
    const unsigned short* b1      = wp + 788480;
    const unsigned short* w2      = wp + 789504;
    const unsigned short* b2      = wp + 1051648;
    const unsigned short* n1_g    = wp + 1051904;
    const unsigned short* n1_b    = wp + 1052160;
    const unsigned short* n2_g    = wp + 1052416;
    const unsigned short* n2_b    = wp + 1052672;
    const unsigned short* n3_g    = wp + 1052928;
    const unsigned short* n3_b    = wp + 1053184;

    detect_kernel<<<1, 1, 0, stream>>>((const unsigned int*)d_in[15], flag);

    PtrTable pt;
    for (int i = 0; i < 18; ++i) pt.p[i] = d_in[3 + i];
    cvt_kernel<<<512, 256, 0, stream>>>(pt, flag, wp);

    // phase 0: nan_to_num + convert
    prep_kernel<<<4096, 256, 0, stream>>>(src, Xa, flag, 4194304);
    // phase 1: Y-axis self-attention (seq = C = 64)
    gemm_mfma<<<dim3(512, 6), 256, 0, stream>>>(Xa, 256, y_in_w, 256, y_in_b, nullptr, QKV, 768, 256, 0, 0, nullptr);
    attn_mfma<4, 4, false, false><<<dim3(1024, 8), 64, 0, stream>>>(QKV, mask, 64, 0);
    gemm_mfma<<<dim3(512, 2), 256, 0, stream>>>(QKV, 768, y_out_w, 256, y_out_b, Xa, Xa, 256, 256, 0, 0, nullptr);
    ln_permute_kernel<<<65536, 64, 0, stream>>>(Xa, n1_g, n1_b, Xb, 0, flag);
    // phase 2: X-axis attention (seq = R = 128, split S = 96)
    gemm_mfma<<<dim3(512, 6), 256, 0, stream>>>(Xb, 256, x_in_w, 256, x_in_b, nullptr, QKV, 768, 256, 0, 0, nullptr);
    attn_mfma<6, 6, true, true><<<dim3(512, 8), 64, 0, stream>>>(QKV, mask, 128, 0);
    gemm_mfma<<<dim3(512, 2), 256, 0, stream>>>(QKV, 768, x_out_w, 256, x_out_b, Xb, Xb, 256, 256, 0, 1, split);
    // second X QKV: only k,v (cols 256..768) need recompute — q of qry rows is intact
    gemm_mfma<<<dim3(512, 4), 256, 0, stream>>>(Xb, 256, x_in_w + 65536, 256, x_in_b + 256, nullptr, QKV + 256, 768, 256, 0, 0, nullptr);
    attn_mfma<2, 6, true, true><<<dim3(512, 8), 64, 0, stream>>>(QKV, mask, 128, 96);
    gemm_mfma<<<dim3(512, 2), 256, 0, stream>>>(QKV, 768, x_out_w, 256, x_out_b, Xb, Xb, 256, 256, 0, 2, split);
    ln_permute_kernel<<<65536, 64, 0, stream>>>(Xb, n2_g, n2_b, Xa, 1, flag);
    // phase 3: MLP (hidden split in two 512-halves, HID reuses QKV region)
    gemm_mfma<<<dim3(512, 4), 256, 0, stream>>>(Xa, 256, w1, 256, b1, nullptr, HID, 512, 256, 1, 0, nullptr);
    gemm_mfma<<<dim3(512, 2), 256, 0, stream>>>(HID, 512, w2, 1024, b2, Xa, Xb, 256, 512, 0, 0, nullptr);
    gemm_mfma<<<dim3(512, 4), 256, 0, stream>>>(Xa, 256, w1 + 512 * 256, 256, b1 + 512, nullptr, HID, 512, 256, 1, 0, nullptr);
    gemm_mfma<<<dim3(512, 2), 256, 0, stream>>>(HID, 512, w2 + 512, 1024, nullptr, Xb, Xb, 256, 512, 0, 0, nullptr);
    // phase 4: LN3 -> output (dtype per flag)
    ln_permute_kernel<<<65536, 64, 0, stream>>>(Xb, n3_g, n3_b, d_out, 2, flag);
}

// Round 3
// 676.377 us; speedup vs baseline: 1.1034x; 1.0722x over previous
//
#include <hip/hip_runtime.h>
#include <hip/hip_bf16.h>
#include <math.h>

// TwoAxisTransformerEncoderLayer — bs=8, R=128, C=64, E=256, H=8, hd=32, S=96, MLP=1024
// R8: gemm_mfma v5 — T2 LDS XOR-swizzle via pre-swizzled global source (rule #21:
// linear gload_lds dest + inverse-swizzled SOURCE + swizzled READ). Kills the
// 16-way bank conflict on frag ds_read_b128 (9.83M conflict cyc/dispatch @R7).
// Keeps R7 double-buffered global_load_lds pipeline + XCD bijective swizzle.
// Epilogue and all other kernels unchanged.

#define EDIM 256
#define HD   32
#define SCTX 96

typedef __bf16 bf16x8 __attribute__((ext_vector_type(8)));
typedef float  f32x4  __attribute__((ext_vector_type(4)));
union Frag { bf16x8 v; unsigned short u[8]; };

static __device__ __forceinline__ float b2f(unsigned short u) {
    return __uint_as_float(((unsigned int)u) << 16);
}
static __device__ __forceinline__ unsigned short f2b(float f) {
    unsigned int u = __float_as_uint(f);
    u += 0x7fffu + ((u >> 16) & 1u);           // RNE for finite values
    return (unsigned short)(u >> 16);
}

// async 16B global->LDS (DMA, no VGPR round-trip). dst must be wave-uniform;
// HW writes dst + lane*16.
static __device__ __forceinline__ void gload16(const unsigned short* g, unsigned short* l) {
    __builtin_amdgcn_global_load_lds(
        (const __attribute__((address_space(1))) unsigned int*)g,
        (__attribute__((address_space(3))) unsigned int*)l,
        16, 0, 0);
}

// ---------------------------------------------------------------- dtype detect
__global__ void detect_kernel(const unsigned int* __restrict__ n1g_raw,
                              int* __restrict__ flag) {
    *flag = (*n1g_raw == 0x3F800000u) ? 1 : 0;   // fp32 1.0f vs bf16 pair
}

// ---------------------------------------------------------------- weight pool convert
struct PtrTable { const void* p[18]; };

__global__ void cvt_kernel(PtrTable t, const int* __restrict__ flag,
                           unsigned short* __restrict__ wp) {
    const int seg_off[19] = {0, 196608, 197376, 262912, 263168, 459776, 460544,
                             526080, 526336, 788480, 789504, 1051648, 1051904,
                             1052160, 1052416, 1052672, 1052928, 1053184, 1053440};
    const int f = *flag;
    int idx = blockIdx.x * blockDim.x + threadIdx.x;
    int stride = gridDim.x * blockDim.x;
    for (int i = idx; i < 1053440; i += stride) {
        int s = 0;
        while (i >= seg_off[s + 1]) ++s;
        int j = i - seg_off[s];
        unsigned short o;
        if (f) o = f2b(((const float*)t.p[s])[j]);
        else   o = ((const unsigned short*)t.p[s])[j];
        wp[i] = o;
    }
}

// ---------------------------------------------------------------- nan_to_num + src convert
__global__ void prep_kernel(const void* __restrict__ src,
                            unsigned short* __restrict__ dst,
                            const int* __restrict__ flag, int n4) {
    const int f = *flag;
    int idx = blockIdx.x * blockDim.x + threadIdx.x;
    int stride = gridDim.x * blockDim.x;
    if (f) {
        const float4* s4 = (const float4*)src;
        for (int i = idx; i < n4; i += stride) {
            float4 v = s4[i];
            ushort4 o;
            o.x = ((__float_as_uint(v.x) & 0x7F800000u) == 0x7F800000u) ? 0 : f2b(v.x);
            o.y = ((__float_as_uint(v.y) & 0x7F800000u) == 0x7F800000u) ? 0 : f2b(v.y);
            o.z = ((__float_as_uint(v.z) & 0x7F800000u) == 0x7F800000u) ? 0 : f2b(v.z);
            o.w = ((__float_as_uint(v.w) & 0x7F800000u) == 0x7F800000u) ? 0 : f2b(v.w);
            ((ushort4*)dst)[i] = o;
        }
    } else {
        const ushort4* s4 = (const ushort4*)src;
        for (int i = idx; i < n4; i += stride) {
            ushort4 v = s4[i];
            if ((v.x & 0x7F80u) == 0x7F80u) v.x = 0;
            if ((v.y & 0x7F80u) == 0x7F80u) v.y = 0;
            if ((v.z & 0x7F80u) == 0x7F80u) v.z = 0;
            if ((v.w & 0x7F80u) == 0x7F80u) v.w = 0;
            ((ushort4*)dst)[i] = v;
        }
    }
}

// ---------------------------------------------------------------- MFMA GEMM v5
// out[m,n] = A[m,:K] . W[n,:K] (+bias) (gelu?) (+res[m,n]) -> bf16
// 128x128 tile / 256 threads (4 waves 2x2), BK=64, K % 64 == 0.
// LDS: 64 KB double-buffered [row][64] A,B tiles via global_load_lds dwordx4.
// XOR-swizzle: LDS(row, slot16B) holds global slot (slot ^ (row&7)) — achieved
// by permuting the per-lane GLOBAL source (DMA dest stays linear); frag reads
// XOR the slot back. 16-way bank conflict -> 2-way (free).
// Pipeline: STAGE(t+1) -> compute(t) -> barrier (vmcnt(0) drain).
// Block swizzle: bijective chunked XCD map, n-tile fastest (A strip L2 reuse).
// Epilogue: bias/gelu in regs -> bf16 slab (32x136, aliases LDS) -> vectorized
// res-add + dwordx4 stores. pred: 0=all, 1=(m&127)<S, 2=(m&127)>=S.
__global__ __launch_bounds__(256) void gemm_mfma(
        const unsigned short* __restrict__ A, int lda,
        const unsigned short* __restrict__ W, int ldw,
        const unsigned short* __restrict__ bias,
        const unsigned short* __restrict__ res,
        unsigned short* __restrict__ out, int ldo,
        int K, int fuse, int pred, const int* __restrict__ splitp) {
    __shared__ __align__(16) unsigned short SH[32768];   // 64 KB: A0|B0|A1|B1
    unsigned short* Slab = SH;            // 32x136 (aliases buf0, used post-mainloop)

    const int tid = threadIdx.x;

    // XCD-aware bijective chunked swizzle; all grids here are multiples of 8 blocks.
    const int nT   = gridDim.y;
    const int nwg  = gridDim.x * nT;
    const int flat = blockIdx.y * gridDim.x + blockIdx.x;
    const int cpx  = nwg >> 3;
    const int wgid = (flat & 7) * cpx + (flat >> 3);
    const int m0 = (wgid / nT) * 128;
    const int n0 = (wgid % nT) * 128;

    const int wave = tid >> 6;
    const int lane = tid & 63;
    const int wm = (wave >> 1) << 6;
    const int wn = (wave & 1) << 6;
    const int lm = lane & 15;
    const int lq = lane >> 4;

    // staging map: 16B slot = tid; LDS row rt = tid>>3, LDS slot st = tid&7.
    // Global source slot = st ^ (rt&7)  (inverse swizzle; involution).
    const int rt = tid >> 3;              // row 0..31 (+32 per round j)
    const int ct = (((tid & 7) ^ ((tid >> 3) & 7)) * 8);   // swizzled k-elem offset
    const unsigned short* Ag = A + (size_t)(m0 + rt) * lda + ct;
    const unsigned short* Wg = W + (size_t)(n0 + rt) * ldw + ct;
    const size_t a32 = (size_t)32 * lda, w32 = (size_t)32 * ldw;
    const int wofs = wave * 512;          // wave-uniform LDS base (+2048/round)

    f32x4 acc[4][4] = {};
    const int nk = K >> 6;

    // prologue: stage tile 0 into buf 0
#pragma unroll
    for (int j = 0; j < 4; ++j) {
        gload16(Ag + j * a32, SH + wofs + j * 2048);
        gload16(Wg + j * w32, SH + 8192 + wofs + j * 2048);
    }
    __syncthreads();

    const int rs = lm & 7;                // read-side swizzle key (row & 7)
    int cur = 0;
    for (int t = 0; t < nk; ++t) {
        if (t + 1 < nk) {                  // issue next tile's DMA (in flight under MFMA)
            const int kn = (t + 1) << 6;
            unsigned short* Ad = SH + ((cur ^ 1) << 14) + wofs;
#pragma unroll
            for (int j = 0; j < 4; ++j) {
                gload16(Ag + j * a32 + kn, Ad + j * 2048);
                gload16(Wg + j * w32 + kn, Ad + 8192 + j * 2048);
            }
        }
        const unsigned short* As = SH + (cur << 14);
        const unsigned short* Bs = As + 8192;
#pragma unroll
        for (int kk = 0; kk < 2; ++kk) {
            bf16x8 af[4], bq[4];
#pragma unroll
            for (int i = 0; i < 4; ++i)
                af[i] = *(const bf16x8*)&As[(wm + i * 16 + lm) * 64 + (((kk * 4 + lq) ^ rs) * 8)];
#pragma unroll
            for (int j = 0; j < 4; ++j)
                bq[j] = *(const bf16x8*)&Bs[(wn + j * 16 + lm) * 64 + (((kk * 4 + lq) ^ rs) * 8)];
#pragma unroll
            for (int i = 0; i < 4; ++i)
#pragma unroll
                for (int j = 0; j < 4; ++j)
                    acc[i][j] = __builtin_amdgcn_mfma_f32_16x16x32_bf16(af[i], bq[j], acc[i][j], 0, 0, 0);
        }
        __syncthreads();                   // drains vmcnt: tile t+1 ready; reads done
        cur ^= 1;
    }

    const int S = (pred != 0) ? *splitp : 0;
    float bv[4];
#pragma unroll
    for (int j = 0; j < 4; ++j)
        bv[j] = bias ? b2f(bias[n0 + wn + j * 16 + lm]) : 0.f;

    const int srow = (wave >> 1) * 16 + lq * 4;      // slab row base for this lane
    const int sr2 = tid >> 3;                        // readback slab row 0..31
    const int cc = (tid & 7) * 16;                   // readback col base
    const int mH = (sr2 >> 4) * 64 + (sr2 & 15);     // tile-row (minus i*16)

#pragma unroll
    for (int i = 0; i < 4; ++i) {
#pragma unroll
        for (int j = 0; j < 4; ++j)
#pragma unroll
            for (int r = 0; r < 4; ++r) {
                float x = acc[i][j][r] + bv[j];
                if (fuse == 1) x = 0.5f * x * (1.0f + erff(x * 0.70710678118654752f));
                Slab[(srow + r) * 136 + wn + j * 16 + lm] = f2b(x);
            }
        __syncthreads();
        {
            const int m = m0 + mH + i * 16;
            const int rr = m & 127;
            bool st = true;
            if (pred == 1 && rr >= S) st = false;
            if (pred == 2 && rr < S) st = false;
            if (st) {
#pragma unroll
                for (int h = 0; h < 2; ++h) {
                    uint4 v = *(const uint4*)&Slab[sr2 * 136 + cc + h * 8];
                    if (res) {
                        uint4 rv = *(const uint4*)(res + (size_t)m * 256 + n0 + cc + h * 8);
                        unsigned short* pv = (unsigned short*)&v;
                        const unsigned short* pr = (const unsigned short*)&rv;
#pragma unroll
                        for (int e = 0; e < 8; ++e)
                            pv[e] = f2b(b2f(pv[e]) + b2f(pr[e]));
                    }
                    *(uint4*)(out + (size_t)m * ldo + n0 + cc + h * 8) = v;
                }
            }
        }
        __syncthreads();
    }
}

// ---------------------------------------------------------------- RoPE on 8 consecutive dims
static __device__ __forceinline__ void rope8(float* t, int p0, float pos) {
#pragma unroll
    for (int p = 0; p < 4; ++p) {
        float invf = exp2f((float)(p0 + p) * -0.8304820237193385f);  // 10000^(-i/16)
        float ang = pos * invf;
        float c = __cosf(ang), s = __sinf(ang);
        float xe = t[2 * p], xo = t[2 * p + 1];
        t[2 * p]     = xe * c - xo * s;
        t[2 * p + 1] = xe * s + xo * c;
    }
}

// ---------------------------------------------------------------- MFMA attention (R4)
template<int NQT, int NKT, bool ROPE, bool BIAS>
__global__ __launch_bounds__(64) void attn_mfma(unsigned short* __restrict__ QKV,
                                                const int* __restrict__ mask,
                                                int seqlen, int qoff) {
    constexpr int NK = NKT * 16;
    constexpr int KS = NK / 32;
    const int s = blockIdx.x;
    const int h = blockIdx.y;
    const int lane = threadIdx.x;
    const int lm = lane & 15;
    const int lq = lane >> 4;
    const size_t rowbase = (size_t)s * seqlen;
    const float scale = 0.17677669529663689f;   // 1/sqrt(32)

    __shared__ __align__(16) unsigned short Vs[NK][40];
    __shared__ __align__(16) unsigned short Pt[16][104];
    __shared__ float bias_s[NK];

#pragma unroll
    for (int r0 = 0; r0 < NK; r0 += 16) {
        int r = r0 + (lane >> 2);
        int c = (lane & 3) * 8;
        uint4 v = *(const uint4*)(QKV + (rowbase + r) * 768 + 512 + h * 32 + c);
        *(uint4*)&Vs[r][c] = v;
    }
    if (BIAS) {
        const int b = s >> 6;
        for (int r = lane; r < NK; r += 64)
            bias_s[r] = (mask[b * 128 + r] > 0) ? 0.f : -1e9f;
    }
    Frag kf[NKT];
#pragma unroll
    for (int nt = 0; nt < NKT; ++nt) {
        const int krow = nt * 16 + lm;
        const unsigned short* kp = QKV + (rowbase + krow) * 768 + 256 + h * 32 + lq * 8;
        float t[8];
#pragma unroll
        for (int j = 0; j < 8; ++j) t[j] = b2f(kp[j]);
        if (ROPE) rope8(t, lq * 4, (float)krow);
#pragma unroll
        for (int j = 0; j < 8; ++j) kf[nt].u[j] = f2b(t[j]);
    }
    __syncthreads();
    Frag bvf[KS][2];
#pragma unroll
    for (int ks = 0; ks < KS; ++ks)
#pragma unroll
        for (int dt = 0; dt < 2; ++dt)
#pragma unroll
            for (int j = 0; j < 8; ++j)
                bvf[ks][dt].u[j] = Vs[ks * 32 + lq * 8 + j][dt * 16 + lm];

    for (int mt = 0; mt < NQT; ++mt) {
        Frag qf;
        const int qrow = qoff + mt * 16 + lm;
        {
            const unsigned short* qp = QKV + (rowbase + qrow) * 768 + h * 32 + lq * 8;
            float t[8];
#pragma unroll
            for (int j = 0; j < 8; ++j) t[j] = b2f(qp[j]);
            if (ROPE) rope8(t, lq * 4, (float)qrow);
#pragma unroll
            for (int j = 0; j < 8; ++j) qf.u[j] = f2b(t[j]);
        }
        f32x4 sacc[NKT] = {};
#pragma unroll
        for (int nt = 0; nt < NKT; ++nt)
            sacc[nt] = __builtin_amdgcn_mfma_f32_16x16x32_bf16(qf.v, kf[nt].v, sacc[nt], 0, 0, 0);
        float pv[NKT][4], mx[4], sm[4], inv[4];
#pragma unroll
        for (int r = 0; r < 4; ++r) mx[r] = -3.0e38f;
#pragma unroll
        for (int nt = 0; nt < NKT; ++nt)
#pragma unroll
            for (int r = 0; r < 4; ++r) {
                float x = sacc[nt][r] * scale;
                if (BIAS) x += bias_s[nt * 16 + lm];
                pv[nt][r] = x;
                mx[r] = fmaxf(mx[r], x);
            }
#pragma unroll
        for (int m = 1; m < 16; m <<= 1)
#pragma unroll
            for (int r = 0; r < 4; ++r) mx[r] = fmaxf(mx[r], __shfl_xor(mx[r], m, 64));
#pragma unroll
        for (int r = 0; r < 4; ++r) sm[r] = 0.f;
#pragma unroll
        for (int nt = 0; nt < NKT; ++nt)
#pragma unroll
            for (int r = 0; r < 4; ++r) {
                float p = __expf(pv[nt][r] - mx[r]);
                pv[nt][r] = p;
                sm[r] += p;
            }
#pragma unroll
        for (int m = 1; m < 16; m <<= 1)
#pragma unroll
            for (int r = 0; r < 4; ++r) sm[r] += __shfl_xor(sm[r], m, 64);
#pragma unroll
        for (int r = 0; r < 4; ++r) inv[r] = 1.f / sm[r];
#pragma unroll
        for (int nt = 0; nt < NKT; ++nt)
#pragma unroll
            for (int r = 0; r < 4; ++r)
                Pt[lq * 4 + r][nt * 16 + lm] = f2b(pv[nt][r] * inv[r]);
        __syncthreads();
        f32x4 oacc[2] = {};
#pragma unroll
        for (int ks = 0; ks < KS; ++ks) {
            Frag af;
            af.v = *(const bf16x8*)&Pt[lm][ks * 32 + lq * 8];
#pragma unroll
            for (int dt = 0; dt < 2; ++dt)
                oacc[dt] = __builtin_amdgcn_mfma_f32_16x16x32_bf16(af.v, bvf[ks][dt].v, oacc[dt], 0, 0, 0);
        }
#pragma unroll
        for (int dt = 0; dt < 2; ++dt)
#pragma unroll
            for (int r = 0; r < 4; ++r) {
                const int m = qoff + mt * 16 + lq * 4 + r;
                QKV[(rowbase + m) * 768 + h * 32 + dt * 16 + lm] = f2b(oacc[dt][r]);
            }
        __syncthreads();
    }
}

// ---------------------------------------------------------------- LayerNorm (+permute)
__global__ __launch_bounds__(64) void ln_permute_kernel(
        const unsigned short* __restrict__ X,
        const unsigned short* __restrict__ gam,
        const unsigned short* __restrict__ bet,
        void* __restrict__ Y, int mode, const int* __restrict__ flag) {
    const int t = blockIdx.x;
    const int tid = threadIdx.x;
    const int e = tid << 2;
    ushort4 xv = *(const ushort4*)(X + (size_t)t * EDIM + e);
    float v0 = b2f(xv.x), v1 = b2f(xv.y), v2 = b2f(xv.z), v3 = b2f(xv.w);
    float s = v0 + v1 + v2 + v3;
#pragma unroll
    for (int m = 32; m > 0; m >>= 1) s += __shfl_xor(s, m, 64);
    float mean = s * (1.f / EDIM);
    float d0 = v0 - mean, d1 = v1 - mean, d2 = v2 - mean, d3 = v3 - mean;
    float q = d0 * d0 + d1 * d1 + d2 * d2 + d3 * d3;
#pragma unroll
    for (int m = 32; m > 0; m >>= 1) q += __shfl_xor(q, m, 64);
    float rstd = rsqrtf(q * (1.f / EDIM) + 1e-5f);
    float g0 = b2f(gam[e]), g1 = b2f(gam[e + 1]), g2 = b2f(gam[e + 2]), g3 = b2f(gam[e + 3]);
    float b0 = b2f(bet[e]), b1 = b2f(bet[e + 1]), b2_ = b2f(bet[e + 2]), b3 = b2f(bet[e + 3]);
    float y0 = d0 * rstd * g0 + b0;
    float y1 = d1 * rstd * g1 + b1;
    float y2 = d2 * rstd * g2 + b2_;
    float y3 = d3 * rstd * g3 + b3;
    size_t drow;
    if (mode == 0) {
        int b = t >> 13, r = (t >> 6) & 127, c = t & 63;
        drow = ((size_t)b << 13) + ((size_t)c << 7) + (size_t)r;
    } else if (mode == 1) {
        int b = t >> 13, c = (t >> 7) & 63, r = t & 127;
        drow = ((size_t)b << 13) + ((size_t)r << 6) + (size_t)c;
    } else {
        drow = (size_t)t;
    }
    if (mode == 2 && *flag) {
        float4 o4 = make_float4(y0, y1, y2, y3);
        *(float4*)((float*)Y + drow * EDIM + e) = o4;
    } else {
        ushort4 o;
        o.x = f2b(y0); o.y = f2b(y1); o.z = f2b(y2); o.w = f2b(y3);
        *(ushort4*)((unsigned short*)Y + drow * EDIM + e) = o;
    }
}

// ---------------------------------------------------------------- launch
extern "C" void kernel_launch(void* const* d_in, const int* in_sizes, int n_in,
                              void* d_out, int out_size, void* d_ws, size_t ws_size,
                              hipStream_t stream) {
    (void)in_sizes; (void)n_in; (void)out_size; (void)ws_size;
    const void* src  = d_in[0];
    const int*  mask = (const int*)d_in[1];
    const int*  split= (const int*)d_in[2];

    int*            flag = (int*)d_ws;
    unsigned short* wp   = (unsigned short*)((char*)d_ws + 1024);
    unsigned short* Xa   = (unsigned short*)((char*)d_ws + (size_t)4 * 1024 * 1024);
    unsigned short* Xb   = Xa + (size_t)16777216;
    unsigned short* QKV  = Xb + (size_t)16777216;
    unsigned short* HID  = QKV;

    const unsigned short* y_in_w  = wp + 0;
    const unsigned short* y_in_b  = wp + 196608;
    const unsigned short* y_out_w = wp + 197376;
    const unsigned short* y_out_b = wp + 262912;
    const unsigned short* x_in_w  = wp + 263168;
    const unsigned short* x_in_b  = wp + 459776;
    const unsigned short* x_out_w = wp + 460544;
    const unsigned short* x_out_b = wp + 526080;
    const unsigned short* w1      = wp + 526336;
    const unsigned short* b1      = wp + 788480;
    const unsigned short* w2      = wp + 789504;
    const unsigned short* b2      = wp + 1051648;
    const unsigned short* n1_g    = wp + 1051904;
    const unsigned short* n1_b    = wp + 1052160;
    const unsigned short* n2_g    = wp + 1052416;
    const unsigned short* n2_b    = wp + 1052672;
    const unsigned short* n3_g    = wp + 1052928;
    const unsigned short* n3_b    = wp + 1053184;

    detect_kernel<<<1, 1, 0, stream>>>((const unsigned int*)d_in[15], flag);

    PtrTable pt;
    for (int i = 0; i < 18; ++i) pt.p[i] = d_in[3 + i];
    cvt_kernel<<<512, 256, 0, stream>>>(pt, flag, wp);

    // phase 0: nan_to_num + convert
    prep_kernel<<<4096, 256, 0, stream>>>(src, Xa, flag, 4194304);
    // phase 1: Y-axis self-attention (seq = C = 64)
    gemm_mfma<<<dim3(512, 6), 256, 0, stream>>>(Xa, 256, y_in_w, 256, y_in_b, nullptr, QKV, 768, 256, 0, 0, nullptr);
    attn_mfma<4, 4, false, false><<<dim3(1024, 8), 64, 0, stream>>>(QKV, mask, 64, 0);
    gemm_mfma<<<dim3(512, 2), 256, 0, stream>>>(QKV, 768, y_out_w, 256, y_out_b, Xa, Xa, 256, 256, 0, 0, nullptr);
    ln_permute_kernel<<<65536, 64, 0, stream>>>(Xa, n1_g, n1_b, Xb, 0, flag);
    // phase 2: X-axis attention (seq = R = 128, split S = 96)
    gemm_mfma<<<dim3(512, 6), 256, 0, stream>>>(Xb, 256, x_in_w, 256, x_in_b, nullptr, QKV, 768, 256, 0, 0, nullptr);
    attn_mfma<6, 6, true, true><<<dim3(512, 8), 64, 0, stream>>>(QKV, mask, 128, 0);
    gemm_mfma<<<dim3(512, 2), 256, 0, stream>>>(QKV, 768, x_out_w, 256, x_out_b, Xb, Xb, 256, 256, 0, 1, split);
    // second X QKV: only k,v (cols 256..768) need recompute — q of qry rows is intact
    gemm_mfma<<<dim3(512, 4), 256, 0, stream>>>(Xb, 256, x_in_w + 65536, 256, x_in_b + 256, nullptr, QKV + 256, 768, 256, 0, 0, nullptr);
    attn_mfma<2, 6, true, true><<<dim3(512, 8), 64, 0, stream>>>(QKV, mask, 128, 96);
    gemm_mfma<<<dim3(512, 2), 256, 0, stream>>>(QKV, 768, x_out_w, 256, x_out_b, Xb, Xb, 256, 256, 0, 2, split);
    ln_permute_kernel<<<65536, 64, 0, stream>>>(Xb, n2_g, n2_b, Xa, 1, flag);
    // phase 3: MLP (hidden split in two 512-halves, HID reuses QKV region)
    gemm_mfma<<<dim3(512, 4), 256, 0, stream>>>(Xa, 256, w1, 256, b1, nullptr, HID, 512, 256, 1, 0, nullptr);
    gemm_mfma<<<dim3(512, 2), 256, 0, stream>>>(HID, 512, w2, 1024, b2, Xa, Xb, 256, 512, 0, 0, nullptr);
    gemm_mfma<<<dim3(512, 4), 256, 0, stream>>>(Xa, 256, w1 + 512 * 256, 256, b1 + 512, nullptr, HID, 512, 256, 1, 0, nullptr);
    gemm_mfma<<<dim3(512, 2), 256, 0, stream>>>(HID, 512, w2 + 512, 1024, nullptr, Xb, Xb, 256, 512, 0, 0, nullptr);
    // phase 4: LN3 -> output (dtype per flag)
    ln_permute_kernel<<<65536, 64, 0, stream>>>(Xb, n3_g, n3_b, d_out, 2, flag);
}